// Round 6
// baseline (21.069 us; speedup 1.0000x reference)
//
#include <hip/hip_runtime.h>

typedef short  bf16x8 __attribute__((ext_vector_type(8)));
typedef float  f32x4  __attribute__((ext_vector_type(4)));

#define HP 4

// ---------------------------------------------------------------------------
// Fused kernel v3: one block per (n, i-PAIR). 112 blocks x 768 threads.
//
// Block b: n = b/28, pr = b%28, covers center rows i0 = 4+2*pr and i0+1.
// Needs B rows i0-4 .. i0+5 (10) and A rows i0, i0+1 (2) -> 12 rows staged
// (vs 20 for two separate blocks: -40% global fetch).
//
// Phase 1 (12 waves, one row each, no cross-wave coupling, ONE barrier):
//   lane = w; 64 raw fp32 loads -> regs, per-lane ss (norms applied AFTER
//   MFMA: dot(a^,b^) = raw * inva[j] * invb[j']), RTN->bf16, ds_write_b128
//   into padded LDS tiles [row][w][72].
//
// Phase 2: 16 tasks = (iloc, band m, col-tile ti); task t: il=t>>3, m=t&3,
//   ti=(t>>2)&1; col tile ntv=m+ti (ntv==4 -> zeros). Waves 0..11 take task
//   wib; waves 0..3 also take task 12+wib. 18 MFMAs per task.
//
// Finish: per-block partial -> release-store to slots[b]; fetch_add counter;
//   the block seeing old==111 acquire-loads all 112 slots in fixed order,
//   sums deterministically, writes d_out. Counter zeroed per replay by a
//   4-byte hipMemsetAsync node.
// ---------------------------------------------------------------------------
__global__ __launch_bounds__(768) void fused_kernel(const float* __restrict__ A,
                                                    const float* __restrict__ B,
                                                    float* __restrict__ slots,
                                                    unsigned int* __restrict__ counter,
                                                    float* __restrict__ out) {
    __shared__ ushort bt[10][64][72];     // 92,160 B raw-bf16 B rows
    __shared__ ushort at[2][64][72];      // 18,432 B raw-bf16 A rows
    __shared__ float  binv[10][64];       //  2,560 B
    __shared__ float  ainv_s[2][64];      //    512 B
    __shared__ float  s_lds[2][2][4][16]; //  1,024 B  [il][ti][m][j16]
    __shared__ float  sx_lds[2][2][4][16];//  1,024 B
    __shared__ float  red[2];
    __shared__ unsigned int lastflag;

    // Bijective XCD swizzle (112 = 8 * 14): i-neighbors share an L2
    const int b0 = blockIdx.x;
    const int b  = (b0 & 7) * 14 + (b0 >> 3);
    const int n  = b / 28;
    const int pr = b - n * 28;
    const int i0 = 4 + 2 * pr;                 // 4..58; centers i0, i0+1
    const int t  = threadIdx.x, wib = t >> 6, l = t & 63;

    // ---- Phase 1: wave wib stages its single row (0..9 -> B, 10..11 -> A)
    {
        const int r = wib;
        const int hrow = (r < 10) ? (i0 - HP + r) : (i0 + (r - 10));
        const float* src = ((r < 10) ? B : A) + (size_t)n * 262144 + (size_t)hrow * 64 + l;
        ushort* dst = ((r < 10) ? &bt[r][0][0] : &at[r - 10][0][0]) + l * 72;

        float v[64];
        #pragma unroll
        for (int c = 0; c < 64; ++c) v[c] = src[(size_t)c * 4096];

        float ss0 = 0.f, ss1 = 0.f, ss2 = 0.f, ss3 = 0.f;
        #pragma unroll
        for (int c = 0; c < 64; c += 4) {
            ss0 = fmaf(v[c],   v[c],   ss0);
            ss1 = fmaf(v[c+1], v[c+1], ss1);
            ss2 = fmaf(v[c+2], v[c+2], ss2);
            ss3 = fmaf(v[c+3], v[c+3], ss3);
        }
        #pragma unroll
        for (int c0 = 0; c0 < 64; c0 += 8) {
            uint pk[4];
            #pragma unroll
            for (int q = 0; q < 4; ++q) {
                uint u0 = __float_as_uint(v[c0 + 2*q]);     u0 = (u0 + 0x7FFFu + ((u0 >> 16) & 1)) >> 16;
                uint u1 = __float_as_uint(v[c0 + 2*q + 1]); u1 = (u1 + 0x7FFFu + ((u1 >> 16) & 1)) >> 16;
                pk[q] = u0 | (u1 << 16);
            }
            *(uint4*)(dst + c0) = *(const uint4*)pk;    // 16B aligned (144|16, 2*c0|16)
        }
        const float inv = 1.0f / (sqrtf((ss0 + ss1) + (ss2 + ss3)) + 1e-8f);
        if (r < 10) binv[r][l] = inv; else ainv_s[r - 10][l] = inv;
    }
    __syncthreads();

    // ---- Phase 2: tasks over waves
    const int lo = l & 15, hi = l >> 4;
    #pragma unroll
    for (int rep = 0; rep < 2; ++rep) {
        if (rep == 1 && wib >= 4) break;         // wave-uniform
        const int task = (rep == 0) ? wib : (12 + wib);
        const int il = task >> 3;                // 0..1
        const int m  = task & 3;
        const int ti = (task >> 2) & 1;
        const int ntv = m + ti;                  // 0..4 (4 = idle -> zeros)
        const int j0  = HP + m * 16;
        const int arow_l = min(j0 + lo, 63);     // clamped lanes feed only masked rows
        const bf16x8 a0 = *(const bf16x8*)&at[il][arow_l][hi * 8];
        const bf16x8 a1 = *(const bf16x8*)&at[il][arow_l][hi * 8 + 32];

        int jrow[4]; float av[4];
        #pragma unroll
        for (int r = 0; r < 4; ++r) {
            jrow[r] = j0 + hi * 4 + r;
            av[r]   = ainv_s[il][min(jrow[r], 63)];
        }

        float s_acc[4]  = {0.f, 0.f, 0.f, 0.f};
        float sx_acc[4] = {0.f, 0.f, 0.f, 0.f};

        if (ntv < 4) {
            const int col = ntv * 16 + lo;
            float vm[4];
            #pragma unroll
            for (int r = 0; r < 4; ++r) {
                int d = col - jrow[r];
                vm[r] = (jrow[r] < 60 && d >= -HP && d <= HP) ? 1.0f : 0.0f;
            }
            #pragma unroll
            for (int di = 0; di < 9; ++di) {
                const ushort* q = &bt[il + di][col][hi * 8];
                const bf16x8 bq0 = *(const bf16x8*)q;
                const bf16x8 bq1 = *(const bf16x8*)(q + 32);
                f32x4 acc = __builtin_amdgcn_mfma_f32_16x16x32_bf16(a0, bq0,
                                (f32x4){0.f, 0.f, 0.f, 0.f}, 0, 0, 0);
                acc = __builtin_amdgcn_mfma_f32_16x16x32_bf16(a1, bq1, acc, 0, 0, 0);
                const float bi = binv[il + di][col];
                #pragma unroll
                for (int r = 0; r < 4; ++r) {
                    float p = acc[r] * (av[r] * bi);
                    float e = __expf(p);
                    s_acc[r]  = fmaf(vm[r], e, s_acc[r]);
                    sx_acc[r] = fmaf(vm[r], p, sx_acc[r]);
                }
            }
        }
        // reduce across the 16 col-lanes sharing each output row
        #pragma unroll
        for (int r = 0; r < 4; ++r) {
            #pragma unroll
            for (int off = 1; off < 16; off <<= 1) {
                s_acc[r]  += __shfl_xor(s_acc[r],  off);
                sx_acc[r] += __shfl_xor(sx_acc[r], off);
            }
        }
        if (lo == 0) {
            #pragma unroll
            for (int r = 0; r < 4; ++r) {
                s_lds[il][ti][m][hi * 4 + r]  = s_acc[r];
                sx_lds[il][ti][m][hi * 4 + r] = sx_acc[r];
            }
        }
    }
    __syncthreads();

    // ---- Per-block finish: waves 0,1 handle iloc 0,1 (lane l <-> j = HP+l)
    if (wib < 2) {
        const int il = wib;
        float contrib = 0.f;
        if (l < 56) {
            const int m2 = l >> 4, rib = l & 15;
            float s  = s_lds[il][0][m2][rib]  + s_lds[il][1][m2][rib];
            float sx = sx_lds[il][0][m2][rib] + sx_lds[il][1][m2][rib];
            contrib = 81.0f * __logf(s) - sx;
        }
        #pragma unroll
        for (int off = 32; off; off >>= 1) contrib += __shfl_xor(contrib, off);
        if (l == 0) red[il] = contrib;
    }
    __syncthreads();

    // ---- Publish + last-done-block gather
    if (t == 0) {
        const float part = red[0] + red[1];
        __hip_atomic_store(&slots[b], part, __ATOMIC_RELEASE, __HIP_MEMORY_SCOPE_AGENT);
        const unsigned int old = __hip_atomic_fetch_add(counter, 1u, __ATOMIC_ACQ_REL,
                                                        __HIP_MEMORY_SCOPE_AGENT);
        lastflag = (old == 111u) ? 1u : 0u;
    }
    __syncthreads();
    if (lastflag && wib == 0) {
        float s = 0.f;
        if (l < 56) {
            float v0 = __hip_atomic_load(&slots[l],      __ATOMIC_ACQUIRE, __HIP_MEMORY_SCOPE_AGENT);
            float v1 = __hip_atomic_load(&slots[l + 56], __ATOMIC_ACQUIRE, __HIP_MEMORY_SCOPE_AGENT);
            s = v0 + v1;
        }
        #pragma unroll
        for (int off = 32; off; off >>= 1) s += __shfl_xor(s, off);
        if (l == 0) out[0] = s;
    }
}

extern "C" void kernel_launch(void* const* d_in, const int* in_sizes, int n_in,
                              void* d_out, int out_size, void* d_ws, size_t ws_size,
                              hipStream_t stream) {
    // inputs: 0=featsA(unused) 1=warpedA 2=tensorB 3=warp_grid(unused) 4=patch_size(=9)
    const float* warpedA = (const float*)d_in[1];
    const float* tensorB = (const float*)d_in[2];
    float* slots = (float*)d_ws;                       // 112 floats
    unsigned int* counter = (unsigned int*)(slots + 112);
    float* out = (float*)d_out;

    hipMemsetAsync(counter, 0, sizeof(unsigned int), stream);   // capture-safe
    fused_kernel<<<112, 768, 0, stream>>>(warpedA, tensorB, slots, counter, out);
}

// Round 7
// 13.656 us; speedup vs baseline: 1.5428x; 1.5428x over previous
//
#include <hip/hip_runtime.h>

typedef short  bf16x8 __attribute__((ext_vector_type(8)));
typedef float  f32x4  __attribute__((ext_vector_type(4)));

#define HP 4

// ---------------------------------------------------------------------------
// Fused kernel (R4 skeleton + R5 internals): one block per (n, i) center-row.
// 224 blocks x 640 threads, two graph nodes total, no atomics.
//
// Phase 1 (10 waves, ONE row each, zero cross-wave coupling, one barrier):
//   wave w stages row w (0..8 -> B rows i-4..i+4, 9 -> A row i). Lane = w;
//   64 raw fp32 loads into regs (single row-load latency), per-lane ss
//   (norms applied AFTER MFMA: dot(a^,b^) = raw * inva[j] * invb[j']),
//   RTN->bf16, ds_write_b128 into padded LDS tiles [w][72].
//
// Phase 2 (8 waves in parallel): wave = (band m = w&3, col-tile ti = w>>2),
//   col tile ntv = m+ti (4 -> zeros). 9 di x 2 MFMA = 18 MFMAs per wave;
//   scale by inva*invb, band-mask, accumulate sum-exp/sum-x; s/sx merge
//   additively in LDS (log after merge), 56 parallel logs in wave 0.
//
// Finish: plain store partials[b]; tiny 1-wave reduce kernel -> d_out.
// ---------------------------------------------------------------------------
__global__ __launch_bounds__(640) void fused_kernel(const float* __restrict__ A,
                                                    const float* __restrict__ B,
                                                    float* __restrict__ partials) {
    __shared__ ushort bt[9][64][72];   // 82,944 B raw-bf16 B rows
    __shared__ ushort at[64][72];      //  9,216 B raw-bf16 A row
    __shared__ float  binv[9][64];
    __shared__ float  ainv_s[64];
    __shared__ float  s_lds[8][16];
    __shared__ float  sx_lds[8][16];

    // Bijective XCD swizzle (224 = 8 * 28): i-neighbors share an L2
    const int b0 = blockIdx.x;
    const int b  = (b0 & 7) * 28 + (b0 >> 3);
    const int n  = b / 56;
    const int i  = b - n * 56 + HP;          // 4..59
    const int t  = threadIdx.x, wib = t >> 6, l = t & 63;

    // ---- Phase 1: wave wib stages its single row
    {
        const int r = wib;                   // 0..9, wave-uniform
        const int hrow = (r == 9) ? i : (i - HP + r);
        const float* src = ((r == 9) ? A : B) + (size_t)n * 262144 + (size_t)hrow * 64 + l;
        ushort* dst = ((r == 9) ? &at[0][0] : &bt[r][0][0]) + l * 72;

        float v[64];
        #pragma unroll
        for (int c = 0; c < 64; ++c) v[c] = src[(size_t)c * 4096];

        float ss0 = 0.f, ss1 = 0.f, ss2 = 0.f, ss3 = 0.f;
        #pragma unroll
        for (int c = 0; c < 64; c += 4) {
            ss0 = fmaf(v[c],   v[c],   ss0);
            ss1 = fmaf(v[c+1], v[c+1], ss1);
            ss2 = fmaf(v[c+2], v[c+2], ss2);
            ss3 = fmaf(v[c+3], v[c+3], ss3);
        }
        #pragma unroll
        for (int c0 = 0; c0 < 64; c0 += 8) {
            uint pk[4];
            #pragma unroll
            for (int q = 0; q < 4; ++q) {
                uint u0 = __float_as_uint(v[c0 + 2*q]);     u0 = (u0 + 0x7FFFu + ((u0 >> 16) & 1)) >> 16;
                uint u1 = __float_as_uint(v[c0 + 2*q + 1]); u1 = (u1 + 0x7FFFu + ((u1 >> 16) & 1)) >> 16;
                pk[q] = u0 | (u1 << 16);
            }
            *(uint4*)(dst + c0) = *(const uint4*)pk;   // 16B aligned (144|16, 2*c0|16)
        }
        const float inv = 1.0f / (sqrtf((ss0 + ss1) + (ss2 + ss3)) + 1e-8f);
        if (r == 9) ainv_s[l] = inv; else binv[r][l] = inv;
    }
    __syncthreads();

    // ---- Phase 2: 8 waves, wave = (band m, col-tile ti)
    const int lo = l & 15, hi = l >> 4;
    if (wib < 8) {
        const int m   = wib & 3, ti = wib >> 2;
        const int ntv = m + ti;                  // 0..4 (4 = idle -> zeros)
        const int j0  = HP + m * 16;
        const int arow_l = min(j0 + lo, 63);     // clamped lanes feed only masked rows
        const bf16x8 a0 = *(const bf16x8*)&at[arow_l][hi * 8];
        const bf16x8 a1 = *(const bf16x8*)&at[arow_l][hi * 8 + 32];

        int jrow[4]; float av[4];
        #pragma unroll
        for (int r = 0; r < 4; ++r) {
            jrow[r] = j0 + hi * 4 + r;
            av[r]   = ainv_s[min(jrow[r], 63)];
        }

        float s_acc[4]  = {0.f, 0.f, 0.f, 0.f};
        float sx_acc[4] = {0.f, 0.f, 0.f, 0.f};

        if (ntv < 4) {
            const int col = ntv * 16 + lo;
            float vm[4];
            #pragma unroll
            for (int r = 0; r < 4; ++r) {
                int d = col - jrow[r];
                vm[r] = (jrow[r] < 60 && d >= -HP && d <= HP) ? 1.0f : 0.0f;
            }
            #pragma unroll
            for (int di = 0; di < 9; ++di) {
                const ushort* q = &bt[di][col][hi * 8];
                const bf16x8 bq0 = *(const bf16x8*)q;
                const bf16x8 bq1 = *(const bf16x8*)(q + 32);
                f32x4 acc = __builtin_amdgcn_mfma_f32_16x16x32_bf16(a0, bq0,
                                (f32x4){0.f, 0.f, 0.f, 0.f}, 0, 0, 0);
                acc = __builtin_amdgcn_mfma_f32_16x16x32_bf16(a1, bq1, acc, 0, 0, 0);
                const float bi = binv[di][col];
                #pragma unroll
                for (int r = 0; r < 4; ++r) {
                    float p = acc[r] * (av[r] * bi);
                    float e = __expf(p);
                    s_acc[r]  = fmaf(vm[r], e, s_acc[r]);
                    sx_acc[r] = fmaf(vm[r], p, sx_acc[r]);
                }
            }
        }
        // reduce across the 16 col-lanes sharing each output row
        #pragma unroll
        for (int r = 0; r < 4; ++r) {
            #pragma unroll
            for (int off = 1; off < 16; off <<= 1) {
                s_acc[r]  += __shfl_xor(s_acc[r],  off);
                sx_acc[r] += __shfl_xor(sx_acc[r], off);
            }
        }
        if (lo == 0) {
            #pragma unroll
            for (int r = 0; r < 4; ++r) {
                s_lds[wib][hi * 4 + r]  = s_acc[r];
                sx_lds[wib][hi * 4 + r] = sx_acc[r];
            }
        }
    }
    __syncthreads();

    // ---- Per-block finish (wave 0): lane l <-> center j = HP + l
    if (wib == 0) {
        float contrib = 0.f;
        if (l < 56) {
            const int m2 = l >> 4, rib = l & 15;
            float s  = s_lds[m2][rib]  + s_lds[m2 + 4][rib];
            float sx = sx_lds[m2][rib] + sx_lds[m2 + 4][rib];
            contrib = 81.0f * __logf(s) - sx;
        }
        #pragma unroll
        for (int off = 32; off; off >>= 1) contrib += __shfl_xor(contrib, off);
        if (l == 0) partials[b] = contrib;
    }
}

// ---------------------------------------------------------------------------
// Final reduce: one wave sums 224 partials -> d_out[0] (deterministic)
// ---------------------------------------------------------------------------
__global__ __launch_bounds__(64) void reduce_kernel(const float* __restrict__ partials,
                                                    float* __restrict__ out) {
    const int t = threadIdx.x;
    float s = 0.f;
    #pragma unroll
    for (int k = 0; k < 4; ++k) {
        int idx = k * 64 + t;
        if (idx < 224) s += partials[idx];
    }
    #pragma unroll
    for (int off = 32; off; off >>= 1) s += __shfl_xor(s, off);
    if (t == 0) out[0] = s;
}

extern "C" void kernel_launch(void* const* d_in, const int* in_sizes, int n_in,
                              void* d_out, int out_size, void* d_ws, size_t ws_size,
                              hipStream_t stream) {
    // inputs: 0=featsA(unused) 1=warpedA 2=tensorB 3=warp_grid(unused) 4=patch_size(=9)
    const float* warpedA = (const float*)d_in[1];
    const float* tensorB = (const float*)d_in[2];
    float* partials = (float*)d_ws;          // 224 floats
    float* out = (float*)d_out;

    fused_kernel<<<224, 640, 0, stream>>>(warpedA, tensorB, partials);
    reduce_kernel<<<1, 64, 0, stream>>>(partials, out);
}

// Round 8
// 12.993 us; speedup vs baseline: 1.6216x; 1.0510x over previous
//
#include <hip/hip_runtime.h>

typedef short  bf16x8 __attribute__((ext_vector_type(8)));
typedef float  f32x4  __attribute__((ext_vector_type(4)));

#define HP 4

// ---------------------------------------------------------------------------
// Fused kernel: one block per (n, i) center-row. 224 blocks x 896 threads.
//
// Phase 1 (waves 0..9, ONE row each, zero coupling, one barrier): wave w
//   stages row w (0..8 -> B rows i-4..i+4, 9 -> A row i). Lane = w-coord;
//   64 raw fp32 loads into regs, per-lane ss (norms applied AFTER MFMA:
//   dot(a^,b^) = raw * inva[j] * invb[j']), v_cvt_pk_bf16_f32 pack (1 instr
//   per pair), ds_write_b128 into padded LDS tiles [w][72].
//
// Phase 2 (14 waves): half-task per wave: tt = w%7 -> (m = tt&3, ti = tt>>2),
//   half = w/7 -> di range [0,5) or [5,9). 8-10 MFMAs per wave (halved
//   chain vs R7's 18). s/sx merge additively in LDS; 56 parallel logs.
//
// Finish: plain store partials[b]; 1-wave reduce kernel -> d_out.
// ---------------------------------------------------------------------------
__global__ __launch_bounds__(896) void fused_kernel(const float* __restrict__ A,
                                                    const float* __restrict__ B,
                                                    float* __restrict__ partials) {
    __shared__ ushort bt[9][64][72];   // 82,944 B raw-bf16 B rows
    __shared__ ushort at[64][72];      //  9,216 B raw-bf16 A row
    __shared__ float  binv[9][64];
    __shared__ float  ainv_s[64];
    __shared__ float  s_lds[14][16];
    __shared__ float  sx_lds[14][16];

    // Bijective XCD swizzle (224 = 8 * 28): i-neighbors share an L2
    const int b0 = blockIdx.x;
    const int b  = (b0 & 7) * 28 + (b0 >> 3);
    const int n  = b / 56;
    const int i  = b - n * 56 + HP;          // 4..59
    const int t  = threadIdx.x, wib = t >> 6, l = t & 63;

    // ---- Phase 1: waves 0..9 stage one row each (10..13 idle to barrier)
    if (wib < 10) {
        const int r = wib;                   // wave-uniform
        const int hrow = (r == 9) ? i : (i - HP + r);
        const float* src = ((r == 9) ? A : B) + (size_t)n * 262144 + (size_t)hrow * 64 + l;
        ushort* dst = ((r == 9) ? &at[0][0] : &bt[r][0][0]) + l * 72;

        float v[64];
        #pragma unroll
        for (int c = 0; c < 64; ++c) v[c] = src[(size_t)c * 4096];

        float ss0 = 0.f, ss1 = 0.f, ss2 = 0.f, ss3 = 0.f;
        #pragma unroll
        for (int c = 0; c < 64; c += 4) {
            ss0 = fmaf(v[c],   v[c],   ss0);
            ss1 = fmaf(v[c+1], v[c+1], ss1);
            ss2 = fmaf(v[c+2], v[c+2], ss2);
            ss3 = fmaf(v[c+3], v[c+3], ss3);
        }
        #pragma unroll
        for (int c0 = 0; c0 < 64; c0 += 8) {
            uint pk[4];
            #pragma unroll
            for (int q = 0; q < 4; ++q)
                asm("v_cvt_pk_bf16_f32 %0, %1, %2"
                    : "=v"(pk[q]) : "v"(v[c0 + 2*q]), "v"(v[c0 + 2*q + 1]));
            *(uint4*)(dst + c0) = *(const uint4*)pk;   // 16B aligned (144|16, 2*c0|16)
        }
        const float inv = 1.0f / (sqrtf((ss0 + ss1) + (ss2 + ss3)) + 1e-8f);
        if (r == 9) ainv_s[l] = inv; else binv[r][l] = inv;
    }
    __syncthreads();

    // ---- Phase 2: 14 waves, wave = (task tt = w%7, di-half = w/7)
    const int lo = l & 15, hi = l >> 4;
    {
        const int tt   = (wib >= 7) ? (wib - 7) : wib;   // 0..6
        const int half = (wib >= 7) ? 1 : 0;
        const int m    = tt & 3, ti = tt >> 2;           // ti=1 only for m<=2
        const int ntv  = m + ti;                         // 0..3 (always valid)
        const int j0   = HP + m * 16;
        const int arow_l = min(j0 + lo, 63);             // clamped lanes feed masked rows
        const bf16x8 a0 = *(const bf16x8*)&at[arow_l][hi * 8];
        const bf16x8 a1 = *(const bf16x8*)&at[arow_l][hi * 8 + 32];

        int jrow[4]; float av[4];
        #pragma unroll
        for (int r = 0; r < 4; ++r) {
            jrow[r] = j0 + hi * 4 + r;
            av[r]   = ainv_s[min(jrow[r], 63)];
        }

        const int col = ntv * 16 + lo;
        float vm[4];
        #pragma unroll
        for (int r = 0; r < 4; ++r) {
            int d = col - jrow[r];
            vm[r] = (jrow[r] < 60 && d >= -HP && d <= HP) ? 1.0f : 0.0f;
        }

        float s_acc[4]  = {0.f, 0.f, 0.f, 0.f};
        float sx_acc[4] = {0.f, 0.f, 0.f, 0.f};

        const int d0 = half ? 5 : 0, d1 = half ? 9 : 5;
        for (int di = d0; di < d1; ++di) {
            const ushort* q = &bt[di][col][hi * 8];
            const bf16x8 bq0 = *(const bf16x8*)q;
            const bf16x8 bq1 = *(const bf16x8*)(q + 32);
            f32x4 acc = __builtin_amdgcn_mfma_f32_16x16x32_bf16(a0, bq0,
                            (f32x4){0.f, 0.f, 0.f, 0.f}, 0, 0, 0);
            acc = __builtin_amdgcn_mfma_f32_16x16x32_bf16(a1, bq1, acc, 0, 0, 0);
            const float bi = binv[di][col];
            #pragma unroll
            for (int r = 0; r < 4; ++r) {
                float p = acc[r] * (av[r] * bi);
                float e = __expf(p);
                s_acc[r]  = fmaf(vm[r], e, s_acc[r]);
                sx_acc[r] = fmaf(vm[r], p, sx_acc[r]);
            }
        }
        // reduce across the 16 col-lanes sharing each output row
        #pragma unroll
        for (int r = 0; r < 4; ++r) {
            #pragma unroll
            for (int off = 1; off < 16; off <<= 1) {
                s_acc[r]  += __shfl_xor(s_acc[r],  off);
                sx_acc[r] += __shfl_xor(sx_acc[r], off);
            }
        }
        if (lo == 0) {
            #pragma unroll
            for (int r = 0; r < 4; ++r) {
                s_lds[wib][hi * 4 + r]  = s_acc[r];
                sx_lds[wib][hi * 4 + r] = sx_acc[r];
            }
        }
    }
    __syncthreads();

    // ---- Per-block finish (wave 0): lane l <-> center j = HP + l
    // Band m2 gathers waves {m2, m2+7} plus {m2+4, m2+11} when m2 < 3.
    if (wib == 0) {
        float contrib = 0.f;
        if (l < 56) {
            const int m2 = l >> 4, rib = l & 15;
            float s  = s_lds[m2][rib]  + s_lds[m2 + 7][rib];
            float sx = sx_lds[m2][rib] + sx_lds[m2 + 7][rib];
            if (m2 < 3) {
                s  += s_lds[m2 + 4][rib]  + s_lds[m2 + 11][rib];
                sx += sx_lds[m2 + 4][rib] + sx_lds[m2 + 11][rib];
            }
            contrib = 81.0f * __logf(s) - sx;
        }
        #pragma unroll
        for (int off = 32; off; off >>= 1) contrib += __shfl_xor(contrib, off);
        if (l == 0) partials[b] = contrib;
    }
}

// ---------------------------------------------------------------------------
// Final reduce: one wave sums 224 partials -> d_out[0] (deterministic)
// ---------------------------------------------------------------------------
__global__ __launch_bounds__(64) void reduce_kernel(const float* __restrict__ partials,
                                                    float* __restrict__ out) {
    const int t = threadIdx.x;
    float s = 0.f;
    #pragma unroll
    for (int k = 0; k < 4; ++k) {
        int idx = k * 64 + t;
        if (idx < 224) s += partials[idx];
    }
    #pragma unroll
    for (int off = 32; off; off >>= 1) s += __shfl_xor(s, off);
    if (t == 0) out[0] = s;
}

extern "C" void kernel_launch(void* const* d_in, const int* in_sizes, int n_in,
                              void* d_out, int out_size, void* d_ws, size_t ws_size,
                              hipStream_t stream) {
    // inputs: 0=featsA(unused) 1=warpedA 2=tensorB 3=warp_grid(unused) 4=patch_size(=9)
    const float* warpedA = (const float*)d_in[1];
    const float* tensorB = (const float*)d_in[2];
    float* partials = (float*)d_ws;          // 224 floats
    float* out = (float*)d_out;

    fused_kernel<<<224, 896, 0, stream>>>(warpedA, tensorB, partials);
    reduce_kernel<<<1, 64, 0, stream>>>(partials, out);
}